// Round 8
// baseline (472.614 us; speedup 1.0000x reference)
//
#include <hip/hip_runtime.h>

typedef short  s16x8 __attribute__((ext_vector_type(8)));
typedef float  f32x4 __attribute__((ext_vector_type(4)));

#define B_   4
#define N_   1024
#define C_   1024
#define H_   16
#define D_   64
#define LC_  4096
#define LT_  5120
#define KVHALF_ 16777216   // B*H*LC*D elements

// fixed-max softmax constants: p = exp2(s*C1 - C2), C1=0.125*log2e, C2=14*log2e
#define SM_C1 0.18033688011f
#define SM_C2 20.1977305724f

// --- fp32 -> bf16 RNE bit-twiddle (proven; round-5's cvt_pk asm corrupted) --
static __device__ __forceinline__ unsigned short f2bf(float x) {
    union { float f; unsigned int u; } c; c.f = x;
    unsigned int r = (c.u + 0x7FFFu + ((c.u >> 16) & 1u)) >> 16;
    return (unsigned short)r;
}
// round-half-up (2 ops) — used only for P (hot path)
static __device__ __forceinline__ unsigned short pbf(float x) {
    union { float f; unsigned int u; } c; c.f = x;
    return (unsigned short)((c.u + 0x8000u) >> 16);
}
static __device__ __forceinline__ s16x8 cvt8f(const float* p) {
    f32x4 a = *(const f32x4*)p;
    f32x4 b = *(const f32x4*)(p + 4);
    s16x8 r;
#pragma unroll
    for (int j = 0; j < 4; ++j) {
        r[j]     = (short)f2bf(a[j]);
        r[j + 4] = (short)f2bf(b[j]);
    }
    return r;
}
static __device__ __forceinline__ f32x4 mfma16(s16x8 a, s16x8 b, f32x4 c) {
    return __builtin_amdgcn_mfma_f32_16x16x32_bf16(a, b, c, 0, 0, 0);
}
template <int DT>
static __device__ __forceinline__ s16x8 load8(const void* base, size_t eidx) {
    if constexpr (DT == 0) return cvt8f((const float*)base + eidx);
    else return *(const s16x8*)((const unsigned short*)base + eidx);
}

// --- swizzled LDS addressing (halfword index); XOR of 8-elem (16B) blocks --
static __device__ __forceinline__ int vt_addr(int d, int k) {      // VT[d][k] s72
    return d * 72 + ((((k >> 3) ^ ((d >> 3) & 7)) & 7) << 3) + (k & 7);
}
static __device__ __forceinline__ int p_addr(int r, int k) {       // P[row][k] s72
    return r * 72 + ((((k >> 3) ^ ((r >> 2) & 7)) & 7) << 3) + (k & 7);
}
static __device__ __forceinline__ int bt_addr(int n, int k) {      // BT[n][k<32] s40
    return n * 40 + ((((k >> 3) ^ (n >> 3)) & 3) << 3) + (k & 7);
}

// ---------------------------------------------------------------------------
// K-cache convert: elementwise fp32 -> bf16, layout preserved [bh][L][D]
// ---------------------------------------------------------------------------
__global__ __launch_bounds__(256) void convert_k(const float* __restrict__ src,
                                                 unsigned short* __restrict__ dst)
{
    const size_t total8 = (size_t)KVHALF_ / 8;
    size_t stride = (size_t)gridDim.x * blockDim.x;
    for (size_t i = blockIdx.x * blockDim.x + threadIdx.x; i < total8; i += stride)
        *(s16x8*)(dst + i * 8) = cvt8f(src + i * 8);
}

// ---------------------------------------------------------------------------
// V-cache transpose+convert: [bh][L][D] fp32 -> [bh][D][L] bf16 (64x64 tiles)
// ---------------------------------------------------------------------------
__global__ __launch_bounds__(256) void transpose_v(const float* __restrict__ vsrc,
                                                   unsigned short* __restrict__ vdst)
{
    __shared__ __attribute__((aligned(16))) unsigned short tlds[64 * 72];
    const int tid = threadIdx.x;
    const int bh = blockIdx.x >> 6;
    const int l0 = (blockIdx.x & 63) * 64;
    {
        const int lrow = tid >> 2, d0 = (tid & 3) * 16;
        const float* p = vsrc + ((size_t)bh * LC_ + l0 + lrow) * D_ + d0;
        s16x8 a = cvt8f(p), b = cvt8f(p + 8);
#pragma unroll
        for (int j = 0; j < 8; ++j) {
            tlds[vt_addr(d0 + j, lrow)]     = (unsigned short)a[j];
            tlds[vt_addr(d0 + 8 + j, lrow)] = (unsigned short)b[j];
        }
    }
    __syncthreads();
    {
        const int d = tid >> 2, lo = (tid & 3) * 16;
        const int kb = lo >> 3, sd = (d >> 3) & 7;
        s16x8 v0 = *(const s16x8*)&tlds[d * 72 + ((kb ^ sd) << 3)];
        s16x8 v1 = *(const s16x8*)&tlds[d * 72 + (((kb + 1) ^ sd) << 3)];
        unsigned short* q = vdst + ((size_t)bh * D_ + d) * LC_ + l0 + lo;
        *(s16x8*)q = v0;
        *(s16x8*)(q + 8) = v1;
    }
}

// ---------------------------------------------------------------------------
// GEMM: out[M][NW] = A[M][K] @ Bw[K][NW]  (-> bf16 LDS -> MFMA fp32 acc)
// 64x64 tile, BK=32, 4 waves. MODE 0: scatter QKV (v transposed); MODE 1: +bias fp32.
// ---------------------------------------------------------------------------
template <int NW, int MODE, int DTA>
__global__ __launch_bounds__(256) void gemm_k(
    const void* __restrict__ A,
    const float* __restrict__ Bw,
    const float* __restrict__ bias,
    unsigned short* __restrict__ out0,
    unsigned short* __restrict__ out1,
    unsigned short* __restrict__ out2,
    float* __restrict__ outf,
    int K)
{
    __shared__ __attribute__((aligned(16))) unsigned short Alds[64 * 40];
    __shared__ __attribute__((aligned(16))) unsigned short BT[64 * 40];

    const int tid = threadIdx.x;
    const int w  = tid >> 6;
    const int l  = tid & 63;
    const int g  = l >> 4;
    const int li = l & 15;
    const int bm = blockIdx.y * 64;
    const int bn = blockIdx.x * 64;

    f32x4 acc[4] = {};

    for (int k0 = 0; k0 < K; k0 += 32) {
        {
            int row = tid >> 2, ko = (tid & 3) * 8;
            *(s16x8*)&Alds[row * 40 + ko] =
                load8<DTA>(A, (size_t)(bm + row) * K + k0 + ko);
        }
        {
            int kk = tid >> 3, no = (tid & 7) * 8;
            s16x8 v = cvt8f(Bw + (size_t)(k0 + kk) * NW + bn + no);
#pragma unroll
            for (int j = 0; j < 8; ++j)
                BT[bt_addr(no + j, kk)] = (unsigned short)v[j];
        }
        __syncthreads();

        s16x8 a = *(const s16x8*)&Alds[(w * 16 + li) * 40 + g * 8];
#pragma unroll
        for (int ct = 0; ct < 4; ++ct) {
            s16x8 b = *(const s16x8*)&BT[bt_addr(ct * 16 + li, g * 8)];
            acc[ct] = mfma16(a, b, acc[ct]);
        }
        __syncthreads();
    }

    if (MODE == 0) {
        const int which = bn >> 10;            // 0:q 1:k 2:v
        const int h     = (bn & 1023) >> 6;
        const int b     = bm >> 10;
#pragma unroll
        for (int ct = 0; ct < 4; ++ct) {
            const int d = ct * 16 + li;
#pragma unroll
            for (int r = 0; r < 4; ++r) {
                int m = bm + w * 16 + g * 4 + r;
                int n = m & 1023;
                unsigned short val = f2bf(acc[ct][r]);
                if (which == 0)
                    out0[((size_t)((b * H_ + h) * N_ + n)) * D_ + d] = val;
                else if (which == 1)
                    out1[((size_t)((b * H_ + h) * N_ + n)) * D_ + d] = val;
                else // v: transposed [bh][D][N]
                    out2[((size_t)((b * H_ + h) * D_ + d)) * N_ + n] = val;
            }
        }
    } else {
#pragma unroll
        for (int ct = 0; ct < 4; ++ct) {
            const int c = bn + ct * 16 + li;
            const float bv = bias[c];
#pragma unroll
            for (int r = 0; r < 4; ++r) {
                int m = bm + w * 16 + g * 4 + r;
                outf[(size_t)m * NW + c] = acc[ct][r] + bv;
            }
        }
    }
}

// ---------------------------------------------------------------------------
// Flash attention. QBLK=128: 1 block = (b,h, 128 q-rows), 4 waves x 32 rows
// (2 row-groups of 16 sharing every K/V fragment read -> ~half LDS reads per
// unit work). Fixed-max softmax, MFMA ones-column denominator, T14 prefetch.
// ---------------------------------------------------------------------------
__global__ __launch_bounds__(256, 4) void attn_kernel(
    const unsigned short* __restrict__ qbuf,
    const unsigned short* __restrict__ knew,
    const unsigned short* __restrict__ vnewT,
    const unsigned short* __restrict__ kcbf,
    const unsigned short* __restrict__ vtcbf,
    unsigned short* __restrict__ x2)
{
    __shared__ __attribute__((aligned(16))) unsigned short Klds[64 * 72];  // [key][d] linear
    __shared__ __attribute__((aligned(16))) unsigned short VT[80 * 72];    // [d][key] swz; rows 64..79 ones
    __shared__ __attribute__((aligned(16))) unsigned short Plds[128 * 72]; // [row][key] swz

    const int tid  = threadIdx.x;
    const int w    = tid >> 6;
    const int l    = tid & 63;
    const int g    = l >> 4;
    const int li   = l & 15;

    const int i0   = blockIdx.x;          // grid = 512
    const int xcd  = i0 & 7;              // XCD-affinity decode (8 bh per XCD)
    const int j0   = i0 >> 3;
    const int bh   = xcd * 8 + (j0 >> 3);
    const int qblk = j0 & 7;

    // ones block for denominator: VT row 64 = 1.0, rows 65..79 = 0
    {
        const int row = 64 + (tid >> 4);
        const int c0 = (tid & 15) * 4;
        const unsigned short val = (row == 64) ? (unsigned short)0x3F80 : (unsigned short)0;
#pragma unroll
        for (int j = 0; j < 4; ++j) VT[vt_addr(row, c0 + j)] = val;
    }

    // Q fragments: rows qblk*128 + w*32 + rg*16 + li
    const unsigned short* qbase =
        qbuf + ((size_t)bh * N_ + qblk * 128 + w * 32 + li) * D_;
    const s16x8 qf00 = *(const s16x8*)(qbase + g * 8);
    const s16x8 qf01 = *(const s16x8*)(qbase + 32 + g * 8);
    const s16x8 qf10 = *(const s16x8*)(qbase + 16 * D_ + g * 8);
    const s16x8 qf11 = *(const s16x8*)(qbase + 16 * D_ + 32 + g * 8);

    f32x4 acc0[5] = {};   // row-group 0: [0..3] O cols, [4] denominator
    f32x4 acc1[5] = {};   // row-group 1

    const int kr = tid >> 2;          // key-row (K) / d-row (V)
    const int ko = (tid & 3) * 16;
    s16x8 kreg0, kreg1, vreg0, vreg1; // T14 prefetch registers

    auto LOAD = [&](int t) {
        const int key0 = t * 64;
        if (t < LC_ / 64) {
            const unsigned short* ks = kcbf + ((size_t)bh * LC_ + key0 + kr) * D_ + ko;
            kreg0 = *(const s16x8*)ks; kreg1 = *(const s16x8*)(ks + 8);
            const unsigned short* vs = vtcbf + ((size_t)bh * D_ + kr) * LC_ + key0 + ko;
            vreg0 = *(const s16x8*)vs; vreg1 = *(const s16x8*)(vs + 8);
        } else {
            const unsigned short* ks = knew + ((size_t)bh * N_ + (key0 - LC_) + kr) * D_ + ko;
            kreg0 = *(const s16x8*)ks; kreg1 = *(const s16x8*)(ks + 8);
            const unsigned short* vs = vnewT + ((size_t)bh * D_ + kr) * N_ + (key0 - LC_) + ko;
            vreg0 = *(const s16x8*)vs; vreg1 = *(const s16x8*)(vs + 8);
        }
    };
    LOAD(0);

    const int kb  = ko >> 3;
    const int sdw = (kr >> 3) & 7;     // VT write swizzle for this thread's d-row
    const int prow0 = w * 32 + li;     // P read rows
    const int prow1 = prow0 + 16;

    for (int t = 0; t < LT_ / 64; ++t) {
        __syncthreads();   // previous tile's LDS consumers done
        *(s16x8*)&Klds[kr * 72 + ko]     = kreg0;
        *(s16x8*)&Klds[kr * 72 + ko + 8] = kreg1;
        *(s16x8*)&VT[kr * 72 + ((kb ^ sdw) << 3)]       = vreg0;
        *(s16x8*)&VT[kr * 72 + (((kb + 1) ^ sdw) << 3)] = vreg1;
        if (t + 1 < LT_ / 64) LOAD(t + 1);   // prefetch next tile
        __syncthreads();   // tile t ready

        // QK^T + softmax, per key-column-block ct; K frags shared by row-groups
#pragma unroll
        for (int ct = 0; ct < 4; ++ct) {
            s16x8 kb0 = *(const s16x8*)&Klds[(ct * 16 + li) * 72 + g * 8];
            s16x8 kb1 = *(const s16x8*)&Klds[(ct * 16 + li) * 72 + 32 + g * 8];
            {
                f32x4 s = {};
                s = mfma16(qf00, kb0, s);
                s = mfma16(qf01, kb1, s);
#pragma unroll
                for (int r = 0; r < 4; ++r) {
                    float p = exp2f(fmaf(s[r], SM_C1, -SM_C2));
                    Plds[p_addr(w * 32 + g * 4 + r, ct * 16 + li)] = pbf(p);
                }
            }
            {
                f32x4 s = {};
                s = mfma16(qf10, kb0, s);
                s = mfma16(qf11, kb1, s);
#pragma unroll
                for (int r = 0; r < 4; ++r) {
                    float p = exp2f(fmaf(s[r], SM_C1, -SM_C2));
                    Plds[p_addr(w * 32 + 16 + g * 4 + r, ct * 16 + li)] = pbf(p);
                }
            }
        }

        // PV + denominator; V frags shared by row-groups
        s16x8 pf00 = *(const s16x8*)&Plds[p_addr(prow0, g * 8)];
        s16x8 pf01 = *(const s16x8*)&Plds[p_addr(prow0, 32 + g * 8)];
        s16x8 pf10 = *(const s16x8*)&Plds[p_addr(prow1, g * 8)];
        s16x8 pf11 = *(const s16x8*)&Plds[p_addr(prow1, 32 + g * 8)];
#pragma unroll
        for (int dt = 0; dt < 5; ++dt) {
            const int vrow = dt * 16 + li;
            const int sd = (vrow >> 3) & 7;
            s16x8 vb0 = *(const s16x8*)&VT[vrow * 72 + ((g ^ sd) << 3)];
            s16x8 vb1 = *(const s16x8*)&VT[vrow * 72 + (((4 + g) ^ sd) << 3)];
            acc0[dt] = mfma16(pf00, vb0, acc0[dt]);
            acc0[dt] = mfma16(pf01, vb1, acc0[dt]);
            acc1[dt] = mfma16(pf10, vb0, acc1[dt]);
            acc1[dt] = mfma16(pf11, vb1, acc1[dt]);
        }
    }

    // denominator lives in col 0 of acc*[4]
    float linv0[4], linv1[4];
#pragma unroll
    for (int r = 0; r < 4; ++r) {
        linv0[r] = 1.0f / __shfl(acc0[4][r], l & 48);
        linv1[r] = 1.0f / __shfl(acc1[4][r], l & 48);
    }
    const int b = bh >> 4, h = bh & 15;
#pragma unroll
    for (int dt = 0; dt < 4; ++dt) {
#pragma unroll
        for (int r = 0; r < 4; ++r) {
            int qrow = qblk * 128 + w * 32 + g * 4 + r;
            x2[((size_t)(b * N_ + qrow)) * C_ + h * D_ + dt * 16 + li] =
                f2bf(acc0[dt][r] * linv0[r]);
            x2[((size_t)(b * N_ + qrow + 16)) * C_ + h * D_ + dt * 16 + li] =
                f2bf(acc1[dt][r] * linv1[r]);
        }
    }
}

// ---------------------------------------------------------------------------
extern "C" void kernel_launch(void* const* d_in, const int* in_sizes, int n_in,
                              void* d_out, int out_size, void* d_ws, size_t ws_size,
                              hipStream_t stream)
{
    const void*  x      = d_in[0];
    const float* kv     = (const float*)d_in[1];
    const float* w_qkv  = (const float*)d_in[2];
    const float* w_proj = (const float*)d_in[3];
    const float* b_proj = (const float*)d_in[4];
    float* out = (float*)d_out;

    // ws: kcbf 33.5MB | vtcbf 33.5MB | q 8MB | knew 8MB | vnewT 8MB | x2 8MB
    unsigned short* kcbf  = (unsigned short*)d_ws;
    unsigned short* vtcbf = kcbf + KVHALF_;
    unsigned short* q     = vtcbf + KVHALF_;
    unsigned short* knew  = q + 4194304;
    unsigned short* vnewT = knew + 4194304;
    unsigned short* x2    = vnewT + 4194304;

    // 0) KV cache: K convert (layout-preserving), V transpose-convert
    convert_k<<<dim3(2048), 256, 0, stream>>>(kv, kcbf);
    transpose_v<<<dim3(64 * 64), 256, 0, stream>>>(kv + KVHALF_, vtcbf);

    // 1) QKV projection -> scatter q/knew (row-major) and vnewT (transposed)
    gemm_k<3072, 0, 0><<<dim3(48, 64), 256, 0, stream>>>(
        x, w_qkv, nullptr, q, knew, vnewT, nullptr, C_);

    // 2) attention: grid = B*H*(N/128)
    attn_kernel<<<dim3(B_ * H_ * (N_ / 128)), 256, 0, stream>>>(
        q, knew, vnewT, kcbf, vtcbf, x2);

    // 3) output projection + bias -> fp32 out
    gemm_k<1024, 1, 1><<<dim3(16, 64), 256, 0, stream>>>(
        x2, w_proj, b_proj, nullptr, nullptr, nullptr, out, C_);
}

// Round 9
// 452.980 us; speedup vs baseline: 1.0433x; 1.0433x over previous
//
#include <hip/hip_runtime.h>

typedef short  s16x8 __attribute__((ext_vector_type(8)));
typedef float  f32x4 __attribute__((ext_vector_type(4)));

#define B_   4
#define N_   1024
#define C_   1024
#define H_   16
#define D_   64
#define LC_  4096
#define LT_  5120
#define KVHALF_ 16777216   // B*H*LC*D elements

// fixed-max softmax constants: p = exp2(s*C1 - C2), C1=0.125*log2e, C2=14*log2e
#define SM_C1 0.18033688011f
#define SM_C2 20.1977305724f

static __device__ __forceinline__ unsigned short f2bf(float x) {
    union { float f; unsigned int u; } c; c.f = x;
    unsigned int r = (c.u + 0x7FFFu + ((c.u >> 16) & 1u)) >> 16;
    return (unsigned short)r;
}
static __device__ __forceinline__ float bf2f(unsigned short b) {
    union { unsigned int u; float f; } c; c.u = ((unsigned int)b) << 16; return c.f;
}
static __device__ __forceinline__ unsigned short pbf(float x) {  // round-half-up, hot path
    union { float f; unsigned int u; } c; c.f = x;
    return (unsigned short)((c.u + 0x8000u) >> 16);
}
static __device__ __forceinline__ s16x8 cvt8f(const float* p) {
    f32x4 a = *(const f32x4*)p;
    f32x4 b = *(const f32x4*)(p + 4);
    s16x8 r;
#pragma unroll
    for (int j = 0; j < 4; ++j) {
        r[j]     = (short)f2bf(a[j]);
        r[j + 4] = (short)f2bf(b[j]);
    }
    return r;
}
static __device__ __forceinline__ f32x4 mfma16(s16x8 a, s16x8 b, f32x4 c) {
    return __builtin_amdgcn_mfma_f32_16x16x32_bf16(a, b, c, 0, 0, 0);
}
template <int DT>
static __device__ __forceinline__ s16x8 load8(const void* base, size_t eidx) {
    if constexpr (DT == 0) return cvt8f((const float*)base + eidx);
    else return *(const s16x8*)((const unsigned short*)base + eidx);
}

// --- swizzled LDS addressing (halfword index); XOR of 8-elem (16B) blocks --
static __device__ __forceinline__ int vt_addr(int d, int k) {      // VT[d][k] s72
    return d * 72 + ((((k >> 3) ^ ((d >> 3) & 7)) & 7) << 3) + (k & 7);
}
static __device__ __forceinline__ int p_addr(int r, int k) {       // P[row][k] s72
    return r * 72 + ((((k >> 3) ^ ((r >> 2) & 7)) & 7) << 3) + (k & 7);
}
static __device__ __forceinline__ int bt_addr(int n, int k) {      // BT[n][k<32] s40
    return n * 40 + ((((k >> 3) ^ (n >> 3)) & 3) << 3) + (k & 7);
}

// ---------------------------------------------------------------------------
__global__ __launch_bounds__(256) void convert_k(const float* __restrict__ src,
                                                 unsigned short* __restrict__ dst)
{
    const size_t total8 = (size_t)KVHALF_ / 8;
    size_t stride = (size_t)gridDim.x * blockDim.x;
    for (size_t i = blockIdx.x * blockDim.x + threadIdx.x; i < total8; i += stride)
        *(s16x8*)(dst + i * 8) = cvt8f(src + i * 8);
}

// V-cache transpose+convert: [bh][L][D] fp32 -> [bh][D][L] bf16 (64x64 tiles)
__global__ __launch_bounds__(256) void transpose_v(const float* __restrict__ vsrc,
                                                   unsigned short* __restrict__ vdst)
{
    __shared__ __attribute__((aligned(16))) unsigned short tlds[64 * 72];
    const int tid = threadIdx.x;
    const int bh = blockIdx.x >> 6;
    const int l0 = (blockIdx.x & 63) * 64;
    {
        const int lrow = tid >> 2, d0 = (tid & 3) * 16;
        const float* p = vsrc + ((size_t)bh * LC_ + l0 + lrow) * D_ + d0;
        s16x8 a = cvt8f(p), b = cvt8f(p + 8);
#pragma unroll
        for (int j = 0; j < 8; ++j) {
            tlds[vt_addr(d0 + j, lrow)]     = (unsigned short)a[j];
            tlds[vt_addr(d0 + 8 + j, lrow)] = (unsigned short)b[j];
        }
    }
    __syncthreads();
    {
        const int d = tid >> 2, lo = (tid & 3) * 16;
        const int kb = lo >> 3, sd = (d >> 3) & 7;
        s16x8 v0 = *(const s16x8*)&tlds[d * 72 + ((kb ^ sd) << 3)];
        s16x8 v1 = *(const s16x8*)&tlds[d * 72 + (((kb + 1) ^ sd) << 3)];
        unsigned short* q = vdst + ((size_t)bh * D_ + d) * LC_ + l0 + lo;
        *(s16x8*)q = v0;
        *(s16x8*)(q + 8) = v1;
    }
}

// ---------------------------------------------------------------------------
// GEMM (unchanged, proven). MODE 0: scatter QKV (v transposed); MODE 1: +bias fp32.
// ---------------------------------------------------------------------------
template <int NW, int MODE, int DTA>
__global__ __launch_bounds__(256) void gemm_k(
    const void* __restrict__ A,
    const float* __restrict__ Bw,
    const float* __restrict__ bias,
    unsigned short* __restrict__ out0,
    unsigned short* __restrict__ out1,
    unsigned short* __restrict__ out2,
    float* __restrict__ outf,
    int K)
{
    __shared__ __attribute__((aligned(16))) unsigned short Alds[64 * 40];
    __shared__ __attribute__((aligned(16))) unsigned short BT[64 * 40];

    const int tid = threadIdx.x;
    const int w  = tid >> 6;
    const int l  = tid & 63;
    const int g  = l >> 4;
    const int li = l & 15;
    const int bm = blockIdx.y * 64;
    const int bn = blockIdx.x * 64;

    f32x4 acc[4] = {};

    for (int k0 = 0; k0 < K; k0 += 32) {
        {
            int row = tid >> 2, ko = (tid & 3) * 8;
            *(s16x8*)&Alds[row * 40 + ko] =
                load8<DTA>(A, (size_t)(bm + row) * K + k0 + ko);
        }
        {
            int kk = tid >> 3, no = (tid & 7) * 8;
            s16x8 v = cvt8f(Bw + (size_t)(k0 + kk) * NW + bn + no);
#pragma unroll
            for (int j = 0; j < 8; ++j)
                BT[bt_addr(no + j, kk)] = (unsigned short)v[j];
        }
        __syncthreads();

        s16x8 a = *(const s16x8*)&Alds[(w * 16 + li) * 40 + g * 8];
#pragma unroll
        for (int ct = 0; ct < 4; ++ct) {
            s16x8 b = *(const s16x8*)&BT[bt_addr(ct * 16 + li, g * 8)];
            acc[ct] = mfma16(a, b, acc[ct]);
        }
        __syncthreads();
    }

    if (MODE == 0) {
        const int which = bn >> 10;
        const int h     = (bn & 1023) >> 6;
        const int b     = bm >> 10;
#pragma unroll
        for (int ct = 0; ct < 4; ++ct) {
            const int d = ct * 16 + li;
#pragma unroll
            for (int r = 0; r < 4; ++r) {
                int m = bm + w * 16 + g * 4 + r;
                int n = m & 1023;
                unsigned short val = f2bf(acc[ct][r]);
                if (which == 0)
                    out0[((size_t)((b * H_ + h) * N_ + n)) * D_ + d] = val;
                else if (which == 1)
                    out1[((size_t)((b * H_ + h) * N_ + n)) * D_ + d] = val;
                else
                    out2[((size_t)((b * H_ + h) * D_ + d)) * N_ + n] = val;
            }
        }
    } else {
#pragma unroll
        for (int ct = 0; ct < 4; ++ct) {
            const int c = bn + ct * 16 + li;
            const float bv = bias[c];
#pragma unroll
            for (int r = 0; r < 4; ++r) {
                int m = bm + w * 16 + g * 4 + r;
                outf[(size_t)m * NW + c] = acc[ct][r] + bv;
            }
        }
    }
}

// ---------------------------------------------------------------------------
// SPLIT attention: QBLK=128 (32 rows/wave, shared K/V frags) x 2 key-halves.
// grid = 1024. Each block: 40 tiles of its half; writes UNNORMALIZED O (bf16)
// + per-row denominator (fp32). Fixed-max softmax => partials are linear.
// ---------------------------------------------------------------------------
__global__ __launch_bounds__(256, 4) void attn_split(
    const unsigned short* __restrict__ qbuf,
    const unsigned short* __restrict__ knew,
    const unsigned short* __restrict__ vnewT,
    const unsigned short* __restrict__ kcbf,
    const unsigned short* __restrict__ vtcbf,
    unsigned short* __restrict__ pO,     // [2][bh][n][d] bf16 unnormalized
    float* __restrict__ pden)            // [2][bh*N] fp32
{
    __shared__ __attribute__((aligned(16))) unsigned short Klds[64 * 72];
    __shared__ __attribute__((aligned(16))) unsigned short VT[80 * 72];
    __shared__ __attribute__((aligned(16))) unsigned short Plds[128 * 72];

    const int tid  = threadIdx.x;
    const int w    = tid >> 6;
    const int l    = tid & 63;
    const int g    = l >> 4;
    const int li   = l & 15;

    const int i0   = blockIdx.x;          // [0,1024)
    const int xcd  = i0 & 7;
    const int j0   = i0 >> 3;             // [0,128)
    const int bh   = xcd * 8 + (j0 >> 4); // [0,64)
    const int sub  = j0 & 15;
    const int half = sub >> 3;            // [0,2)
    const int qblk = sub & 7;             // [0,8)

    // ones block for denominator: VT row 64 = 1.0, rows 65..79 = 0
    {
        const int row = 64 + (tid >> 4);
        const int c0 = (tid & 15) * 4;
        const unsigned short val = (row == 64) ? (unsigned short)0x3F80 : (unsigned short)0;
#pragma unroll
        for (int j = 0; j < 4; ++j) VT[vt_addr(row, c0 + j)] = val;
    }

    const unsigned short* qbase =
        qbuf + ((size_t)bh * N_ + qblk * 128 + w * 32 + li) * D_;
    const s16x8 qf00 = *(const s16x8*)(qbase + g * 8);
    const s16x8 qf01 = *(const s16x8*)(qbase + 32 + g * 8);
    const s16x8 qf10 = *(const s16x8*)(qbase + 16 * D_ + g * 8);
    const s16x8 qf11 = *(const s16x8*)(qbase + 16 * D_ + 32 + g * 8);

    f32x4 acc0[5] = {};
    f32x4 acc1[5] = {};

    const int kr = tid >> 2;
    const int ko = (tid & 3) * 16;
    s16x8 kreg0, kreg1, vreg0, vreg1;

    auto LOAD = [&](int t) {
        const int key0 = t * 64;
        if (t < LC_ / 64) {
            const unsigned short* ks = kcbf + ((size_t)bh * LC_ + key0 + kr) * D_ + ko;
            kreg0 = *(const s16x8*)ks; kreg1 = *(const s16x8*)(ks + 8);
            const unsigned short* vs = vtcbf + ((size_t)bh * D_ + kr) * LC_ + key0 + ko;
            vreg0 = *(const s16x8*)vs; vreg1 = *(const s16x8*)(vs + 8);
        } else {
            const unsigned short* ks = knew + ((size_t)bh * N_ + (key0 - LC_) + kr) * D_ + ko;
            kreg0 = *(const s16x8*)ks; kreg1 = *(const s16x8*)(ks + 8);
            const unsigned short* vs = vnewT + ((size_t)bh * D_ + kr) * N_ + (key0 - LC_) + ko;
            vreg0 = *(const s16x8*)vs; vreg1 = *(const s16x8*)(vs + 8);
        }
    };
    const int t0 = half * 40;             // 40 tiles per half
    LOAD(t0);

    const int kb  = ko >> 3;
    const int sdw = (kr >> 3) & 7;
    const int prow0 = w * 32 + li;
    const int prow1 = prow0 + 16;

    for (int tt = 0; tt < 40; ++tt) {
        const int t = t0 + tt;
        __syncthreads();
        *(s16x8*)&Klds[kr * 72 + ko]     = kreg0;
        *(s16x8*)&Klds[kr * 72 + ko + 8] = kreg1;
        *(s16x8*)&VT[kr * 72 + ((kb ^ sdw) << 3)]       = vreg0;
        *(s16x8*)&VT[kr * 72 + (((kb + 1) ^ sdw) << 3)] = vreg1;
        if (tt + 1 < 40) LOAD(t + 1);
        __syncthreads();

#pragma unroll
        for (int ct = 0; ct < 4; ++ct) {
            s16x8 kb0 = *(const s16x8*)&Klds[(ct * 16 + li) * 72 + g * 8];
            s16x8 kb1 = *(const s16x8*)&Klds[(ct * 16 + li) * 72 + 32 + g * 8];
            {
                f32x4 s = {};
                s = mfma16(qf00, kb0, s);
                s = mfma16(qf01, kb1, s);
#pragma unroll
                for (int r = 0; r < 4; ++r) {
                    float p = exp2f(fmaf(s[r], SM_C1, -SM_C2));
                    Plds[p_addr(w * 32 + g * 4 + r, ct * 16 + li)] = pbf(p);
                }
            }
            {
                f32x4 s = {};
                s = mfma16(qf10, kb0, s);
                s = mfma16(qf11, kb1, s);
#pragma unroll
                for (int r = 0; r < 4; ++r) {
                    float p = exp2f(fmaf(s[r], SM_C1, -SM_C2));
                    Plds[p_addr(w * 32 + 16 + g * 4 + r, ct * 16 + li)] = pbf(p);
                }
            }
        }

        s16x8 pf00 = *(const s16x8*)&Plds[p_addr(prow0, g * 8)];
        s16x8 pf01 = *(const s16x8*)&Plds[p_addr(prow0, 32 + g * 8)];
        s16x8 pf10 = *(const s16x8*)&Plds[p_addr(prow1, g * 8)];
        s16x8 pf11 = *(const s16x8*)&Plds[p_addr(prow1, 32 + g * 8)];
#pragma unroll
        for (int dt = 0; dt < 5; ++dt) {
            const int vrow = dt * 16 + li;
            const int sd = (vrow >> 3) & 7;
            s16x8 vb0 = *(const s16x8*)&VT[vrow * 72 + ((g ^ sd) << 3)];
            s16x8 vb1 = *(const s16x8*)&VT[vrow * 72 + (((4 + g) ^ sd) << 3)];
            acc0[dt] = mfma16(pf00, vb0, acc0[dt]);
            acc0[dt] = mfma16(pf01, vb1, acc0[dt]);
            acc1[dt] = mfma16(pf10, vb0, acc1[dt]);
            acc1[dt] = mfma16(pf11, vb1, acc1[dt]);
        }
    }

    // write unnormalized O (bf16) into pO[half][bh][n][d]
    unsigned short* po = pO + (size_t)half * 4194304;
#pragma unroll
    for (int dt = 0; dt < 4; ++dt) {
#pragma unroll
        for (int r = 0; r < 4; ++r) {
            int row = qblk * 128 + w * 32 + g * 4 + r;
            po[((size_t)bh * N_ + row) * D_ + dt * 16 + li]        = f2bf(acc0[dt][r]);
            po[((size_t)bh * N_ + row + 16) * D_ + dt * 16 + li]   = f2bf(acc1[dt][r]);
        }
    }
    // write denominators (col 0 of acc*[4]): lanes li==0 hold them
    if (li == 0) {
        float* pd = pden + (size_t)half * 65536 + bh * N_;
#pragma unroll
        for (int r = 0; r < 4; ++r) {
            pd[qblk * 128 + w * 32 + g * 4 + r]      = acc0[4][r];
            pd[qblk * 128 + w * 32 + g * 4 + r + 16] = acc1[4][r];
        }
    }
}

// combine: x2[b][n][h*64+d] = (O0+O1)/(den0+den1), bf16
__global__ __launch_bounds__(256) void combine_halves(
    const unsigned short* __restrict__ pO,
    const float* __restrict__ pden,
    unsigned short* __restrict__ x2)
{
    const size_t i8 = (size_t)blockIdx.x * blockDim.x + threadIdx.x; // [0, 524288)
    const size_t idx = i8 * 8;
    const int bh = (int)(idx >> 16);
    const int rem = (int)(idx & 65535);
    const int n = rem >> 6;
    const int d = rem & 63;
    s16x8 a = *(const s16x8*)(pO + idx);
    s16x8 b = *(const s16x8*)(pO + 4194304 + idx);
    const float den = pden[bh * N_ + n] + pden[65536 + bh * N_ + n];
    const float rinv = 1.0f / den;
    const int bb = bh >> 4, h = bh & 15;
    unsigned short* dst = x2 + ((size_t)(bb * N_ + n)) * C_ + h * D_ + d;
    unsigned short o[8];
#pragma unroll
    for (int j = 0; j < 8; ++j)
        o[j] = f2bf((bf2f((unsigned short)a[j]) + bf2f((unsigned short)b[j])) * rinv);
    *(s16x8*)dst = *(s16x8*)o;
}

// ---------------------------------------------------------------------------
// FALLBACK single-pass attention (round-7 proven, 203us): QBLK=64.
// ---------------------------------------------------------------------------
__global__ __launch_bounds__(256) void attn_single(
    const unsigned short* __restrict__ qbuf,
    const unsigned short* __restrict__ knew,
    const unsigned short* __restrict__ vnewT,
    const unsigned short* __restrict__ kcbf,
    const unsigned short* __restrict__ vtcbf,
    unsigned short* __restrict__ x2)
{
    __shared__ __attribute__((aligned(16))) unsigned short Klds[64 * 72];
    __shared__ __attribute__((aligned(16))) unsigned short VT[80 * 72];
    __shared__ __attribute__((aligned(16))) unsigned short Plds[64 * 72];

    const int tid  = threadIdx.x;
    const int w    = tid >> 6;
    const int l    = tid & 63;
    const int g    = l >> 4;
    const int li   = l & 15;

    const int i0   = blockIdx.x;
    const int xcd  = i0 & 7;
    const int j0   = i0 >> 3;
    const int bh   = xcd * 8 + (j0 >> 4);
    const int qblk = j0 & 15;

    {
        const int row = 64 + (tid >> 4);
        const int c0 = (tid & 15) * 4;
        const unsigned short val = (row == 64) ? (unsigned short)0x3F80 : (unsigned short)0;
#pragma unroll
        for (int j = 0; j < 4; ++j) VT[vt_addr(row, c0 + j)] = val;
    }

    const unsigned short* qrowp =
        qbuf + ((size_t)bh * N_ + qblk * 64 + w * 16 + li) * D_;
    const s16x8 qf0 = *(const s16x8*)(qrowp + g * 8);
    const s16x8 qf1 = *(const s16x8*)(qrowp + 32 + g * 8);

    f32x4 acc[5] = {};

    const int kr = tid >> 2;
    const int ko = (tid & 3) * 16;
    s16x8 kreg0, kreg1, vreg0, vreg1;

    auto LOAD = [&](int t) {
        const int key0 = t * 64;
        if (t < LC_ / 64) {
            const unsigned short* ks = kcbf + ((size_t)bh * LC_ + key0 + kr) * D_ + ko;
            kreg0 = *(const s16x8*)ks; kreg1 = *(const s16x8*)(ks + 8);
            const unsigned short* vs = vtcbf + ((size_t)bh * D_ + kr) * LC_ + key0 + ko;
            vreg0 = *(const s16x8*)vs; vreg1 = *(const s16x8*)(vs + 8);
        } else {
            const unsigned short* ks = knew + ((size_t)bh * N_ + (key0 - LC_) + kr) * D_ + ko;
            kreg0 = *(const s16x8*)ks; kreg1 = *(const s16x8*)(ks + 8);
            const unsigned short* vs = vnewT + ((size_t)bh * D_ + kr) * N_ + (key0 - LC_) + ko;
            vreg0 = *(const s16x8*)vs; vreg1 = *(const s16x8*)(vs + 8);
        }
    };
    LOAD(0);

    const int kb  = ko >> 3;
    const int sdw = (kr >> 3) & 7;
    const int prow = w * 16 + li;
    const int sp  = (prow >> 2) & 7;

    for (int t = 0; t < LT_ / 64; ++t) {
        __syncthreads();
        *(s16x8*)&Klds[kr * 72 + ko]     = kreg0;
        *(s16x8*)&Klds[kr * 72 + ko + 8] = kreg1;
        *(s16x8*)&VT[kr * 72 + ((kb ^ sdw) << 3)]       = vreg0;
        *(s16x8*)&VT[kr * 72 + (((kb + 1) ^ sdw) << 3)] = vreg1;
        if (t + 1 < LT_ / 64) LOAD(t + 1);
        __syncthreads();

        f32x4 sc[4];
#pragma unroll
        for (int ct = 0; ct < 4; ++ct) {
            f32x4 s = {};
            s16x8 kb0 = *(const s16x8*)&Klds[(ct * 16 + li) * 72 + g * 8];
            s16x8 kb1 = *(const s16x8*)&Klds[(ct * 16 + li) * 72 + 32 + g * 8];
            s = mfma16(qf0, kb0, s);
            sc[ct] = mfma16(qf1, kb1, s);
        }

#pragma unroll
        for (int ct = 0; ct < 4; ++ct) {
#pragma unroll
            for (int r = 0; r < 4; ++r) {
                float p = exp2f(fmaf(sc[ct][r], SM_C1, -SM_C2));
                Plds[p_addr(w * 16 + g * 4 + r, ct * 16 + li)] = pbf(p);
            }
        }

        s16x8 pf0 = *(const s16x8*)&Plds[prow * 72 + ((g ^ sp) << 3)];
        s16x8 pf1 = *(const s16x8*)&Plds[prow * 72 + (((4 + g) ^ sp) << 3)];
#pragma unroll
        for (int dt = 0; dt < 5; ++dt) {
            const int vrow = dt * 16 + li;
            const int sd = (vrow >> 3) & 7;
            s16x8 vb0 = *(const s16x8*)&VT[vrow * 72 + ((g ^ sd) << 3)];
            s16x8 vb1 = *(const s16x8*)&VT[vrow * 72 + (((4 + g) ^ sd) << 3)];
            acc[dt] = mfma16(pf0, vb0, acc[dt]);
            acc[dt] = mfma16(pf1, vb1, acc[dt]);
        }
    }

    float linv[4];
#pragma unroll
    for (int r = 0; r < 4; ++r)
        linv[r] = 1.0f / __shfl(acc[4][r], l & 48);
    const int b = bh >> 4, h = bh & 15;
#pragma unroll
    for (int dt = 0; dt < 4; ++dt) {
#pragma unroll
        for (int r = 0; r < 4; ++r) {
            int qrow = qblk * 64 + w * 16 + g * 4 + r;
            x2[((size_t)(b * N_ + qrow)) * C_ + h * D_ + dt * 16 + li] =
                f2bf(acc[dt][r] * linv[r]);
        }
    }
}

// ---------------------------------------------------------------------------
extern "C" void kernel_launch(void* const* d_in, const int* in_sizes, int n_in,
                              void* d_out, int out_size, void* d_ws, size_t ws_size,
                              hipStream_t stream)
{
    const void*  x      = d_in[0];
    const float* kv     = (const float*)d_in[1];
    const float* w_qkv  = (const float*)d_in[2];
    const float* w_proj = (const float*)d_in[3];
    const float* b_proj = (const float*)d_in[4];
    float* out = (float*)d_out;

    // common: kcbf 33.5MB | vtcbf 33.5MB | q 8.4MB | knew 8.4MB | vnewT 8.4MB
    unsigned short* kcbf  = (unsigned short*)d_ws;
    unsigned short* vtcbf = kcbf + KVHALF_;
    unsigned short* q     = vtcbf + KVHALF_;
    unsigned short* knew  = q + 4194304;
    unsigned short* vnewT = knew + 4194304;
    unsigned short* tail  = vnewT + 4194304;     // 92.3MB used so far

    // split path extra: pO 2x8.4MB bf16 | pden 0.5MB fp32  (need ~109.6MB)
    const bool split = ws_size >= (size_t)110 * 1024 * 1024 ? true
                     : ws_size >= 109600000u;
    unsigned short* pO   = tail;
    float*          pden = (float*)(tail + 2 * 4194304);
    unsigned short* x2   = split ? q : tail;     // split: combine writes into dead q

    convert_k<<<dim3(2048), 256, 0, stream>>>(kv, kcbf);
    transpose_v<<<dim3(64 * 64), 256, 0, stream>>>(kv + KVHALF_, vtcbf);

    gemm_k<3072, 0, 0><<<dim3(48, 64), 256, 0, stream>>>(
        x, w_qkv, nullptr, q, knew, vnewT, nullptr, C_);

    if (split) {
        attn_split<<<dim3(1024), 256, 0, stream>>>(
            q, knew, vnewT, kcbf, vtcbf, pO, pden);
        combine_halves<<<dim3(2048), 256, 0, stream>>>(pO, pden, x2);
    } else {
        attn_single<<<dim3(B_ * H_ * (N_ / 64)), 256, 0, stream>>>(
            q, knew, vnewT, kcbf, vtcbf, x2);
    }

    gemm_k<1024, 1, 1><<<dim3(16, 64), 256, 0, stream>>>(
        x2, w_proj, b_proj, nullptr, nullptr, nullptr, out, C_);
}